// Round 11
// baseline (300.261 us; speedup 1.0000x reference)
//
#include <hip/hip_runtime.h>
#include <cstdint>
#include <cstddef>

#define N_    32
#define C_    256
#define H_    56
#define W_    56
#define HW_   (H_ * W_)      // 3136
#define NHW_  (N_ * HW_)     // 100352
#define COUT_ 256
#define EPS_  1e-4f
#define PW_   58             // padded width
#define PIMG_ (PW_ * PW_)    // 3364 padded pixels per image

// ---------------------------------------------------------------------------
// Kernel 1a: BN partial sums. 8192 blocks = one (n,c) plane each (32/CU of
// pure float4 streaming; r10's 2048 blocks was only 8/CU).
// ---------------------------------------------------------------------------
__global__ void k_bn_partial(const float* __restrict__ x,
                             float* __restrict__ ps, float* __restrict__ pq) {
    const int c = blockIdx.x >> 5;
    const int n = blockIdx.x & 31;
    const int t = threadIdx.x;
    const float4* p = (const float4*)(x + (size_t)(n * C_ + c) * HW_);
    float sm = 0.f, sq = 0.f;
    for (int i = t; i < HW_ / 4; i += 256) {
        float4 v = p[i];
        sm += v.x + v.y + v.z + v.w;
        sq += v.x * v.x + v.y * v.y + v.z * v.z + v.w * v.w;
    }
    __shared__ float ls[256], lq[256];
    ls[t] = sm; lq[t] = sq;
    __syncthreads();
    for (int off = 128; off >= 1; off >>= 1) {
        if (t < off) { ls[t] += ls[t + off]; lq[t] += lq[t + off]; }
        __syncthreads();
    }
    if (t == 0) { ps[n * C_ + c] = ls[0]; pq[n * C_ + c] = lq[0]; }
}

// ---------------------------------------------------------------------------
// Kernel 1b: finalize per-channel affine: xn = x*a[c] + bb[c]
// ---------------------------------------------------------------------------
__global__ void k_bn_final(const float* __restrict__ ps, const float* __restrict__ pq,
                           const float* __restrict__ gamma, const float* __restrict__ beta,
                           float* __restrict__ a, float* __restrict__ bb) {
    const int c = threadIdx.x;
    float sm = 0.f, sq = 0.f;
    for (int s = 0; s < 32; ++s) { sm += ps[s * C_ + c]; sq += pq[s * C_ + c]; }
    float mu   = sm * (1.f / NHW_);
    float var  = sq * (1.f / NHW_) - mu * mu;
    float rstd = rsqrtf(var + EPS_);
    float g    = gamma[c] * rstd;
    a[c]  = g;
    bb[c] = beta[c] - mu * g;
}

// ---------------------------------------------------------------------------
// Kernel 2: weight prep. alpha, bit-pack sign(W) into TAP-MAJOR layout
// wbits[wd][t][co], and border table ctab[cls][co]. (unchanged from r10)
// ---------------------------------------------------------------------------
__global__ void k_wpack(const float* __restrict__ Wt, float* __restrict__ alpha,
                        uint64_t* __restrict__ wbits, int* __restrict__ ctab) {
    const int co = blockIdx.x;
    const int ci = threadIdx.x;
    const int lane = ci & 63, wave = ci >> 6;      // wave == channel-word wd
    const float* p = Wt + (size_t)(co * C_ + ci) * 9;
    float wv[9];
    float asum = 0.f;
#pragma unroll
    for (int t = 0; t < 9; ++t) { wv[t] = p[t]; asum += fabsf(wv[t]); }
    __shared__ int Pl[9];
    if (ci < 9) Pl[ci] = 0;
    __syncthreads();
#pragma unroll
    for (int t = 0; t < 9; ++t) {
        uint64_t mask = __ballot(wv[t] > 0.f);
        if (lane == 0) {
            wbits[((size_t)wave * 9 + t) * COUT_ + co] = mask;   // [wd][t][co]
            atomicAdd(&Pl[t], (int)__popcll(mask));
        }
    }
    __shared__ float red[256];
    red[ci] = asum;
    __syncthreads();                       // also publishes Pl
    for (int off = 128; off >= 1; off >>= 1) {
        if (ci < off) red[ci] += red[ci + off];
        __syncthreads();
    }
    if (ci == 0) alpha[co] = red[0] * (1.f / 2304.f);
    if (ci < 9) {
        const int rc = ci / 3, cc = ci % 3;
        unsigned m9 = (rc == 0 ? 0x007u : 0u) | (rc == 2 ? 0x1C0u : 0u)
                    | (cc == 0 ? 0x049u : 0u) | (cc == 2 ? 0x124u : 0u);
        int s = 0;
#pragma unroll
        for (int t = 0; t < 9; ++t)
            if ((m9 >> t) & 1) s += 2 * Pl[t] - 256;
        ctab[ci * 256 + co] = s;
    }
}

// ---------------------------------------------------------------------------
// Kernel 3: fused normalize + |xn| partials + sign bit-pack, PIXEL-PAIR form.
// Each thread: 2 adjacent pixels via float2 loads (8 B/lane — G13 sweet
// spot, half the load-instruction count of r10's scalar version). Partial
// |xn| sums go to m4[wd][NHW] NON-atomically (kills 4-way global atomic
// contention and the m memset). Pair never straddles a row (hw even).
// ---------------------------------------------------------------------------
__global__ void k_mpack(const float* __restrict__ x, const float* __restrict__ a,
                        const float* __restrict__ bb, uint64_t* __restrict__ xbits,
                        float* __restrict__ m4) {
    const int q  = blockIdx.x * 256 + threadIdx.x;   // pair index
    const int wd = blockIdx.y;                        // 64-channel word 0..3
    const int p0 = q * 2;
    const int n  = p0 / HW_;
    const int hw = p0 - n * HW_;
    const int h  = hw / W_;
    const int w  = hw - h * W_;        // even -> w+1 <= 55, same row
    const float* xp = x + (size_t)n * C_ * HW_ + (size_t)(wd * 64) * HW_ + hw;
    float ma0 = 0.f, ma1 = 0.f;
    uint64_t b0 = 0, b1 = 0;
#pragma unroll
    for (int j = 0; j < 64; ++j) {
        const int c = wd * 64 + j;
        const float2 v = *(const float2*)(xp + (size_t)j * HW_);
        const float av = a[c], bv = bb[c];
        const float xn0 = fmaf(v.x, av, bv);
        const float xn1 = fmaf(v.y, av, bv);
        ma0 += fabsf(xn0);
        ma1 += fabsf(xn1);
        b0 |= (xn0 > 0.f) ? (1ull << j) : 0ull;
        b1 |= (xn1 > 0.f) ? (1ull << j) : 0ull;
    }
    uint64_t* xw = xbits + ((size_t)wd * N_ + n) * PIMG_ + (size_t)(h + 1) * PW_ + (w + 1);
    xw[0] = b0;
    xw[1] = b1;
    *(float2*)(m4 + (size_t)wd * NHW_ + p0) = make_float2(ma0, ma1);
}

// ---------------------------------------------------------------------------
// Kernel 3b: 3x3 box filter over the 4 m4 partial planes -> beta_map.
// beta = (sum over 9 taps, 4 planes of |xn|-partials) / (9*256). All loads
// L2-hot (1.6 MB working set).
// ---------------------------------------------------------------------------
__global__ void k_box(const float* __restrict__ m4, float* __restrict__ beta_map) {
    const int idx = blockIdx.x * 256 + threadIdx.x;
    if (idx >= NHW_) return;
    const int w = idx % W_;
    const int h = (idx / W_) % H_;
    const int n = idx / HW_;
    float s = 0.f;
#pragma unroll
    for (int dh = 0; dh < 3; ++dh) {
        int ih = h + dh - 1;
        if (ih < 0 || ih >= H_) continue;
#pragma unroll
        for (int dw = 0; dw < 3; ++dw) {
            int iw = w + dw - 1;
            if (iw < 0 || iw >= W_) continue;
            const int off = n * HW_ + ih * W_ + iw;
            s += m4[off] + m4[NHW_ + off] + m4[2 * NHW_ + off] + m4[3 * NHW_ + off];
        }
    }
    beta_map[idx] = s * (1.f / (9.f * 256.f));
}

// ---------------------------------------------------------------------------
// Kernel 4: binary conv, PIXEL-PAIR form — UNCHANGED from r10 (107.8 us,
// occupancy 72%, VALUBusy 96%, per-output VALU at the 144-op floor).
// ---------------------------------------------------------------------------
#define XNP(ACC, X64, W64) do {                                   \
    uint32_t _wl = (uint32_t)(W64), _wh = (uint32_t)((W64) >> 32); \
    uint32_t _xl = (uint32_t)(X64), _xh = (uint32_t)((X64) >> 32); \
    uint32_t _t0, _t1;                                             \
    asm("v_xor_b32 %0, %3, %5\n\t"                                 \
        "v_xor_b32 %1, %4, %6\n\t"                                 \
        "v_bcnt_u32_b32 %2, %0, %2\n\t"                            \
        "v_bcnt_u32_b32 %2, %1, %2"                                \
        : "=&v"(_t0), "=&v"(_t1), "+v"(ACC)                        \
        : "s"(_wl), "s"(_wh), "v"(_xl), "v"(_xh));                 \
} while (0)

__global__ void __launch_bounds__(256, 8)
k_conv(const uint64_t* __restrict__ xbits, const uint64_t* __restrict__ wbits,
       const int* __restrict__ ctab, const float* __restrict__ beta_map,
       const float* __restrict__ alpha, const float* __restrict__ bias,
       float* __restrict__ out) {
    const int idx = blockIdx.x * 512 + (int)threadIdx.x * 2;  // even pixel
    const int grp = blockIdx.y;                                // cout group of 8
    const int n  = idx / HW_;
    const int hw = idx - n * HW_;
    const int h  = hw / W_;
    const int w  = hw - h * W_;      // even; pair (w, w+1) never straddles a row

    int acc0[8], acc1[8];
#pragma unroll
    for (int i = 0; i < 8; ++i) { acc0[i] = 0; acc1[i] = 0; }

#pragma unroll 1
    for (int wd = 0; wd < 4; ++wd) {
        const uint64_t* xp = xbits + ((size_t)wd * N_ + n) * PIMG_
                                   + (size_t)h * PW_ + w;
        const uint64_t* wq = wbits + (size_t)wd * 9 * COUT_ + grp * 8;
#pragma unroll
        for (int r = 0; r < 3; ++r) {
            // 4-wide row segment covers both pixels' 3 taps (16-B aligned:
            // w even, PW even, plane base 16-B aligned)
            const ulonglong2* q = (const ulonglong2*)(xp + r * PW_);
            const ulonglong2 qa = q[0], qb = q[1];
            const uint64_t xv[4] = { qa.x, qa.y, qb.x, qb.y };
#pragma unroll
            for (int c = 0; c < 3; ++c) {
                const uint64_t* wr = wq + (r * 3 + c) * COUT_;  // 64 B contiguous
#pragma unroll
                for (int i = 0; i < 8; ++i) {
                    XNP(acc0[i], xv[c],     wr[i]);
                    XNP(acc1[i], xv[c + 1], wr[i]);
                }
            }
        }
    }

    const int rowcls  = (h == 0) ? 0 : ((h == H_ - 1) ? 2 : 1);
    const int colcls0 = (w == 0) ? 0 : 1;              // w even -> never 55
    const int colcls1 = (w + 1 == W_ - 1) ? 2 : 1;     // w+1 odd -> never 0
    const int* crow0 = ctab + (rowcls * 3 + colcls0) * 256 + grp * 8;
    const int* crow1 = ctab + (rowcls * 3 + colcls1) * 256 + grp * 8;
    const float bm0 = beta_map[idx];
    const float bm1 = beta_map[idx + 1];
    float* op = out + (size_t)n * COUT_ * HW_ + (size_t)(grp * 8) * HW_ + hw;

#pragma unroll
    for (int i = 0; i < 8; ++i) {
        const int co = grp * 8 + i;
        const float al = alpha[co], bi = bias[co];
        const int d0 = 2304 - 2 * acc0[i] + crow0[i];
        const int d1 = 2304 - 2 * acc1[i] + crow1[i];
        const float o0 = fmaxf(((float)d0 + bi) * bm0 * al, 0.f);
        const float o1 = fmaxf(((float)d1 + bi) * bm1 * al, 0.f);
        *(float2*)(op + (size_t)i * HW_) = make_float2(o0, o1);
    }
}

// ---------------------------------------------------------------------------
// Workspace layout (bytes):
//   ps       @ 0        32768     ([32][256] f32)
//   pq       @ 32768    32768
//   a        @ 65536    1024
//   bb       @ 66560    1024
//   alpha    @ 67584    1024
//   ctab     @ 68608    9216
//   wbits    @ 77824    73728     ([wd][t][co] u64, tap-major)
//   xbits    @ 151552   3444736   (planar [wd][32][58][58] u64, memset 0)
//   m4       @ 3596288  1605632   ([wd][NHW] f32 partials, no memset needed)
//   beta_map @ 5201920  401408
//   total    5603328
// ---------------------------------------------------------------------------
extern "C" void kernel_launch(void* const* d_in, const int* in_sizes, int n_in,
                              void* d_out, int out_size, void* d_ws, size_t ws_size,
                              hipStream_t stream) {
    (void)in_sizes; (void)n_in; (void)out_size; (void)ws_size;
    const float* x     = (const float*)d_in[0];
    const float* gamma = (const float*)d_in[1];
    const float* betab = (const float*)d_in[2];
    const float* Wt    = (const float*)d_in[3];
    const float* b     = (const float*)d_in[4];
    float* out = (float*)d_out;

    uint8_t* base = (uint8_t*)d_ws;
    float*    ps       = (float*)(base + 0);
    float*    pq       = (float*)(base + 32768);
    float*    a        = (float*)(base + 65536);
    float*    bb       = (float*)(base + 66560);
    float*    alpha    = (float*)(base + 67584);
    int*      ctab     = (int*)(base + 68608);
    uint64_t* wbits    = (uint64_t*)(base + 77824);
    uint64_t* xbits    = (uint64_t*)(base + 151552);
    float*    m4       = (float*)(base + 3596288);
    float*    beta_map = (float*)(base + 5201920);

    k_bn_partial<<<8192, 256, 0, stream>>>(x, ps, pq);
    k_bn_final<<<1, 256, 0, stream>>>(ps, pq, gamma, betab, a, bb);
    k_wpack<<<COUT_, 256, 0, stream>>>(Wt, alpha, wbits, ctab);
    hipMemsetAsync(xbits, 0, (size_t)N_ * PIMG_ * 4 * sizeof(uint64_t), stream);
    k_mpack<<<dim3(NHW_ / 512, 4), 256, 0, stream>>>(x, a, bb, xbits, m4);
    k_box<<<(NHW_ + 255) / 256, 256, 0, stream>>>(m4, beta_map);
    k_conv<<<dim3(NHW_ / 512, 32), 256, 0, stream>>>(xbits, wbits, ctab, beta_map, alpha, b, out);
}